// Round 1
// baseline (625.093 us; speedup 1.0000x reference)
//
#include <hip/hip_runtime.h>
#include <math.h>

// ---------------------------------------------------------------------------
// InterLevelAttention, MI355X. Fixed shapes from setup_inputs().
// ---------------------------------------------------------------------------
constexpr int B_    = 4;
constexpr int HT    = 64,  WT = 64;
constexpr int HB    = 128, WB = 128;
constexpr int DIM   = 256;           // attn dim
constexpr int KVD   = 512;           // kv_dim (k|v concatenated after proj)
constexpr int HEADS = 8;
constexpr int HD    = 32;
constexpr int NP2   = 16;            // 4x4 window
constexpr int NPIX  = HB * WB;       // 16384 fine pixels / batch
constexpr int NWIN  = HT * WT;       // 4096 windows / batch
constexpr float SCALE = 0.17677669529663687f;  // 32^-0.5

// ---------------------------------------------------------------------------
// Simple fp32 tiled GEMM:  C[M,N] = A[M,K] @ Bw[N,K]^T (+ bias[N])
// 64x64 tile, K-step 16, 256 threads, 4x4 accum per thread.
// M,N multiples of 64; K multiple of 16 (all true here).
// ---------------------------------------------------------------------------
__global__ __launch_bounds__(256) void gemm_nt(
    const float* __restrict__ A, const float* __restrict__ Bw,
    const float* __restrict__ bias, float* __restrict__ C,
    int M, int N, int K)
{
  __shared__ float As[16][68];   // [k][m], pitch 68 keeps 16B alignment
  __shared__ float Bs[16][68];   // [k][n]

  const int tid = threadIdx.x;
  const int m0 = blockIdx.x * 64;
  const int n0 = blockIdx.y * 64;
  const int tx = tid & 15;       // -> 4 cols
  const int ty = tid >> 4;       // -> 4 rows
  const int lr = tid >> 2;       // load row 0..63
  const int lk = (tid & 3) * 4;  // load k-offset 0,4,8,12

  float acc[4][4] = {};

  for (int k0 = 0; k0 < K; k0 += 16) {
    float4 av = *(const float4*)(A  + (size_t)(m0 + lr) * K + k0 + lk);
    float4 bv = *(const float4*)(Bw + (size_t)(n0 + lr) * K + k0 + lk);
    __syncthreads();             // previous iter done reading LDS
    As[lk + 0][lr] = av.x; As[lk + 1][lr] = av.y;
    As[lk + 2][lr] = av.z; As[lk + 3][lr] = av.w;
    Bs[lk + 0][lr] = bv.x; Bs[lk + 1][lr] = bv.y;
    Bs[lk + 2][lr] = bv.z; Bs[lk + 3][lr] = bv.w;
    __syncthreads();
#pragma unroll
    for (int kk = 0; kk < 16; ++kk) {
      float4 a4 = *(const float4*)&As[kk][ty * 4];
      float4 b4 = *(const float4*)&Bs[kk][tx * 4];
      const float ar[4] = {a4.x, a4.y, a4.z, a4.w};
      const float br[4] = {b4.x, b4.y, b4.z, b4.w};
#pragma unroll
      for (int r = 0; r < 4; ++r)
#pragma unroll
        for (int c = 0; c < 4; ++c)
          acc[r][c] = fmaf(ar[r], br[c], acc[r][c]);
    }
  }

#pragma unroll
  for (int r = 0; r < 4; ++r) {
    const int row = m0 + ty * 4 + r;
    const int col = n0 + tx * 4;
    float4 o = make_float4(acc[r][0], acc[r][1], acc[r][2], acc[r][3]);
    if (bias) { o.x += bias[col]; o.y += bias[col+1]; o.z += bias[col+2]; o.w += bias[col+3]; }
    *(float4*)(C + (size_t)row * N + col) = o;
  }
}

// ---------------------------------------------------------------------------
// E[bw, h, p] = exp(scale * <Qpix(pixel(w,p)), K[bw,h]> + rel_init[p] + rel_bias[p])
// One block per window (b,w); threads = (h,d) = 8x32. Padding positions get
// q=0 (value never consumed downstream).
// ---------------------------------------------------------------------------
__global__ __launch_bounds__(256) void e_kernel(
    const float* __restrict__ Qpix, const float* __restrict__ KV,
    const float* __restrict__ rel_init, const float* __restrict__ rel_bias,
    float* __restrict__ E)
{
  const int wg = blockIdx.x;          // b*4096 + w
  const int b  = wg >> 12;
  const int w  = wg & 4095;
  const int i  = w >> 6, j = w & 63;
  const int t  = threadIdx.x;
  const int h  = t >> 5, d = t & 31;

  const float kreg = KV[(size_t)wg * KVD + t];   // t == h*32+d, k-half

  for (int p = 0; p < NP2; ++p) {
    const int y = 2 * i + (p >> 2) - 1;
    const int x = 2 * j + (p & 3) - 1;
    float q = 0.f;
    if ((unsigned)y < (unsigned)HB && (unsigned)x < (unsigned)WB)
      q = Qpix[((size_t)(b * NPIX + y * WB + x)) * DIM + t];
    float part = q * kreg;
#pragma unroll
    for (int off = 16; off; off >>= 1) part += __shfl_xor(part, off, 32);
    if (d == 0) {
      const float logit = part * SCALE + rel_init[p] + rel_bias[p];
      E[(size_t)wg * 128 + h * NP2 + p] = expf(logit);
    }
  }
}

// ---------------------------------------------------------------------------
// S[b,h,y,x] = fold(E): sum of E over all (window,pos) pairs covering pixel.
// One thread per (b,h,y,x).
// ---------------------------------------------------------------------------
__global__ __launch_bounds__(256) void s_kernel(
    const float* __restrict__ E, float* __restrict__ S)
{
  const int idx = blockIdx.x * 256 + threadIdx.x;  // b*131072 + h*16384 + y*128 + x
  const int b  = idx >> 17;
  const int r  = idx & 131071;
  const int h  = r >> 14;
  const int yx = r & 16383;
  const int y  = yx >> 7, x = yx & 127;

  const int ilo = max(0, (y - 1) >> 1), ihi = min(HT - 1, (y + 1) >> 1);
  const int jlo = max(0, (x - 1) >> 1), jhi = min(WT - 1, (x + 1) >> 1);

  float s = 0.f;
  for (int i = ilo; i <= ihi; ++i)
    for (int j = jlo; j <= jhi; ++j) {
      const int p = (y + 1 - 2 * i) * 4 + (x + 1 - 2 * j);
      s += E[((size_t)(b * NWIN + i * WT + j)) * 128 + h * NP2 + p];
    }
  S[idx] = s;
}

// ---------------------------------------------------------------------------
// out_pre[b,pix,c] = sum over covering windows of (E / s_scrambled) * v.
// The reference's _patch_softmax divides a[b,w,h,p] by the folded-sum field
// at SCRAMBLED coords (faithful to its reshape-layout quirk):
//   g = w*128 + h*16 + p;  h_eff = g>>16 = w>>9;  w_eff = (g&0xFFFF)>>4
//     = (w&511)*8 + h;  p_eff = p.
// If pixel(w_eff,p) lands in padding, the divisor is 1 (the where(s==0,1,s)).
// ---------------------------------------------------------------------------
__global__ __launch_bounds__(256) void o_kernel(
    const float* __restrict__ E, const float* __restrict__ S,
    const float* __restrict__ KV, float* __restrict__ out_pre)
{
  const int pg = blockIdx.x;          // b*16384 + y*128 + x
  const int b  = pg >> 14;
  const int yx = pg & 16383;
  const int y  = yx >> 7, x = yx & 127;
  const int t  = threadIdx.x;
  const int h  = t >> 5;

  const int ilo = max(0, (y - 1) >> 1), ihi = min(HT - 1, (y + 1) >> 1);
  const int jlo = max(0, (x - 1) >> 1), jhi = min(WT - 1, (x + 1) >> 1);

  float acc = 0.f;
  for (int i = ilo; i <= ihi; ++i)
    for (int j = jlo; j <= jhi; ++j) {
      const int w = i * WT + j;
      const int p = (y + 1 - 2 * i) * 4 + (x + 1 - 2 * j);
      const float e = E[((size_t)(b * NWIN + w)) * 128 + h * NP2 + p];
      // scrambled denominator lookup
      const int h_eff = w >> 9;
      const int w_eff = ((w & 511) << 3) + h;
      const int i2 = w_eff >> 6, j2 = w_eff & 63;
      const int y2 = 2 * i2 + (p >> 2) - 1;
      const int x2 = 2 * j2 + (p & 3) - 1;
      float s = 1.f;
      if ((unsigned)y2 < (unsigned)HB && (unsigned)x2 < (unsigned)WB)
        s = S[(size_t)((b * HEADS + h_eff) * NPIX) + y2 * WB + x2];
      const float v = KV[((size_t)(b * NWIN + w)) * KVD + 256 + t];
      acc = fmaf(e / s, v, acc);
    }
  out_pre[(size_t)pg * DIM + t] = acc;
}

// ---------------------------------------------------------------------------
extern "C" void kernel_launch(void* const* d_in, const int* in_sizes, int n_in,
                              void* d_out, int out_size, void* d_ws, size_t ws_size,
                              hipStream_t stream) {
  const float* Xt       = (const float*)d_in[0];  // (4, 4096, 512)
  const float* Xb       = (const float*)d_in[1];  // (4, 16384, 256)
  const float* q_w      = (const float*)d_in[2];  // (256, 256)
  const float* kv_w     = (const float*)d_in[3];  // (512, 512)
  const float* proj_w   = (const float*)d_in[4];  // (256, 256)
  const float* proj_b   = (const float*)d_in[5];  // (256,)
  const float* rel_init = (const float*)d_in[6];  // (16,)
  const float* rel_bias = (const float*)d_in[7];  // (16,)
  float* out = (float*)d_out;                     // (4, 16384, 256)

  char* ws = (char*)d_ws;
  const size_t szQ  = (size_t)B_ * NPIX * DIM * sizeof(float);   // 64 MB
  const size_t szKV = (size_t)B_ * NWIN * KVD * sizeof(float);   // 32 MB
  const size_t szE  = (size_t)B_ * NWIN * 128 * sizeof(float);   // 8 MB
  float* Qpix = (float*)ws;                      // aliased as out_pre (safe: o_kernel never reads Qpix)
  float* KV   = (float*)(ws + szQ);
  float* E    = (float*)(ws + szQ + szKV);
  float* S    = (float*)(ws + szQ + szKV + szE); // 2 MB

  const dim3 blk(256);

  // 1) Qpix = Xb @ q_w^T            (65536 x 256 x 256)
  gemm_nt<<<dim3(B_ * NPIX / 64, DIM / 64), blk, 0, stream>>>(
      Xb, q_w, nullptr, Qpix, B_ * NPIX, DIM, DIM);

  // 2) KV = Xt @ kv_w^T             (16384 x 512 x 512)
  gemm_nt<<<dim3(B_ * NWIN / 64, KVD / 64), blk, 0, stream>>>(
      Xt, kv_w, nullptr, KV, B_ * NWIN, KVD, KVD);

  // 3) E = exp(scale*qk + rel)
  e_kernel<<<dim3(B_ * NWIN), blk, 0, stream>>>(Qpix, KV, rel_init, rel_bias, E);

  // 4) S = fold(E)
  s_kernel<<<dim3(B_ * HEADS * NPIX / 256), blk, 0, stream>>>(E, S);

  // 5) out_pre = fold((E/s_scrambled) * v)   [writes into Qpix buffer]
  o_kernel<<<dim3(B_ * NPIX), blk, 0, stream>>>(E, S, KV, Qpix);

  // 6) out = out_pre @ proj_w^T + proj_b
  gemm_nt<<<dim3(B_ * NPIX / 64, DIM / 64), blk, 0, stream>>>(
      Qpix, proj_w, proj_b, out, B_ * NPIX, DIM, DIM);
}

// Round 2
// 387.816 us; speedup vs baseline: 1.6118x; 1.6118x over previous
//
#include <hip/hip_runtime.h>
#include <math.h>

// ---------------------------------------------------------------------------
// InterLevelAttention, MI355X. Fixed shapes from setup_inputs().
// Round 2: bf16 MFMA GEMMs (m97-style 128x128 tile + global_load_lds w=16).
// ---------------------------------------------------------------------------
constexpr int B_    = 4;
constexpr int HT    = 64,  WT = 64;
constexpr int HB    = 128, WB = 128;
constexpr int DIM   = 256;           // attn dim
constexpr int KVD   = 512;           // kv_dim (k|v concatenated after proj)
constexpr int HEADS = 8;
constexpr int NP2   = 16;            // 4x4 window
constexpr int NPIX  = HB * WB;       // 16384 fine pixels / batch
constexpr int NWIN  = HT * WT;       // 4096 windows / batch
constexpr float SCALE = 0.17677669529663687f;  // 32^-0.5

using bf16x8 = __attribute__((ext_vector_type(8))) short;
using f32x4  = __attribute__((ext_vector_type(4))) float;

__device__ __forceinline__ unsigned short f2bf(float f) {
  union { float f; unsigned u; } v; v.f = f;
  unsigned r = v.u + 0x7fffu + ((v.u >> 16) & 1u);   // RNE
  return (unsigned short)(r >> 16);
}
__device__ __forceinline__ float bf2f(unsigned short h) {
  union { unsigned u; float f; } v; v.u = ((unsigned)h) << 16;
  return v.f;
}

// ---------------------------------------------------------------------------
// fp32 -> bf16 cast, 4 elems/thread (float4 in, ushort4 out). n % 1024 == 0.
// ---------------------------------------------------------------------------
__global__ __launch_bounds__(256) void cast_bf16(
    const float* __restrict__ in, unsigned short* __restrict__ out, int n4)
{
  const int i = blockIdx.x * 256 + threadIdx.x;
  if (i >= n4) return;
  float4 v = ((const float4*)in)[i];
  ushort4 o;
  o.x = f2bf(v.x); o.y = f2bf(v.y); o.z = f2bf(v.z); o.w = f2bf(v.w);
  ((ushort4*)out)[i] = o;
}

// ---------------------------------------------------------------------------
// bf16 MFMA GEMM: C[M,N] = A[M,K] @ Bw[N,K]^T (+bias), 128x128 tile, BK=32,
// 256 threads = 4 waves (2x2), 16x16x32 MFMA, global_load_lds width 16.
// M%128==0, N%128==0, K%32==0.
// ---------------------------------------------------------------------------
template<bool BF16_OUT, bool BIAS>
__global__ __launch_bounds__(256) void gemm_bf16(
    const unsigned short* __restrict__ A, const unsigned short* __restrict__ Bw,
    const float* __restrict__ bias, void* __restrict__ C,
    int M, int N, int K)
{
  __shared__ unsigned short Ash[128 * 32];   // [row][k], 64B rows, 8 KB
  __shared__ unsigned short Bsh[128 * 32];

  const int tid  = threadIdx.x;
  const int wave = tid >> 6;
  const int lane = tid & 63;
  const int m0 = blockIdx.x * 128;
  const int n0 = blockIdx.y * 128;
  const int wm = (wave >> 1) * 64;     // wave's 64x64 sub-tile
  const int wn = (wave & 1) * 64;

  // staging chunk map: chunk c (16B) -> row c>>2, k-offset (c&3)*8 elems.
  const int c0 = wave * 64 + lane;     // issue 0: chunks 0..255
  const int c1 = 256 + c0;             // issue 1: chunks 256..511
  const int r0 = c0 >> 2, k0off = (c0 & 3) * 8;
  const int r1 = c1 >> 2, k1off = (c1 & 3) * 8;
  const int ldsOff0 = wave * 1024;         // wave-uniform LDS base, bytes
  const int ldsOff1 = 4096 + wave * 1024;

  f32x4 acc[4][4];
#pragma unroll
  for (int i = 0; i < 4; ++i)
#pragma unroll
    for (int j = 0; j < 4; ++j) { f32x4 z = {0.f, 0.f, 0.f, 0.f}; acc[i][j] = z; }

  const int fr = lane & 15;            // fragment row/col within 16
  const int fk = (lane >> 4) * 8;      // fragment k-offset

  for (int kk = 0; kk < K; kk += 32) {
    __syncthreads();                   // previous iter done reading LDS
    const unsigned short* a0 = A  + (size_t)(m0 + r0) * K + kk + k0off;
    const unsigned short* a1 = A  + (size_t)(m0 + r1) * K + kk + k1off;
    const unsigned short* b0 = Bw + (size_t)(n0 + r0) * K + kk + k0off;
    const unsigned short* b1 = Bw + (size_t)(n0 + r1) * K + kk + k1off;
    __builtin_amdgcn_global_load_lds(
        (const __attribute__((address_space(1))) unsigned int*)a0,
        (__attribute__((address_space(3))) unsigned int*)((char*)Ash + ldsOff0),
        16, 0, 0);
    __builtin_amdgcn_global_load_lds(
        (const __attribute__((address_space(1))) unsigned int*)a1,
        (__attribute__((address_space(3))) unsigned int*)((char*)Ash + ldsOff1),
        16, 0, 0);
    __builtin_amdgcn_global_load_lds(
        (const __attribute__((address_space(1))) unsigned int*)b0,
        (__attribute__((address_space(3))) unsigned int*)((char*)Bsh + ldsOff0),
        16, 0, 0);
    __builtin_amdgcn_global_load_lds(
        (const __attribute__((address_space(1))) unsigned int*)b1,
        (__attribute__((address_space(3))) unsigned int*)((char*)Bsh + ldsOff1),
        16, 0, 0);
    __syncthreads();                   // drains vmcnt before barrier

    bf16x8 af[4], bfr[4];
#pragma unroll
    for (int t = 0; t < 4; ++t) {
      af[t]  = *(const bf16x8*)&Ash[(wm + t * 16 + fr) * 32 + fk];
      bfr[t] = *(const bf16x8*)&Bsh[(wn + t * 16 + fr) * 32 + fk];
    }
#pragma unroll
    for (int mt = 0; mt < 4; ++mt)
#pragma unroll
      for (int nt = 0; nt < 4; ++nt)
        acc[mt][nt] = __builtin_amdgcn_mfma_f32_16x16x32_bf16(
            af[mt], bfr[nt], acc[mt][nt], 0, 0, 0);
  }

  // epilogue: C/D layout col=lane&15, row=(lane>>4)*4+reg
  const int col0 = lane & 15;
  const int rb   = (lane >> 4) * 4;
#pragma unroll
  for (int mt = 0; mt < 4; ++mt) {
#pragma unroll
    for (int nt = 0; nt < 4; ++nt) {
      const int col = n0 + wn + nt * 16 + col0;
      float bv = BIAS ? bias[col] : 0.f;
#pragma unroll
      for (int r = 0; r < 4; ++r) {
        const int row = m0 + wm + mt * 16 + rb + r;
        const float v = acc[mt][nt][r] + bv;
        if (BF16_OUT) ((unsigned short*)C)[(size_t)row * N + col] = f2bf(v);
        else          ((float*)C)[(size_t)row * N + col] = v;
      }
    }
  }
}

// ---------------------------------------------------------------------------
// E[bw, h, p] = exp(scale * <Qpix(pixel(w,p)), K[bw,h]> + rel_init[p] + rel_bias[p])
// One block per window; threads = (h,d) = 8x32.
// ---------------------------------------------------------------------------
__global__ __launch_bounds__(256) void e_kernel(
    const unsigned short* __restrict__ Qh, const unsigned short* __restrict__ KVh,
    const float* __restrict__ rel_init, const float* __restrict__ rel_bias,
    float* __restrict__ E)
{
  const int wg = blockIdx.x;          // b*4096 + w
  const int b  = wg >> 12;
  const int w  = wg & 4095;
  const int i  = w >> 6, j = w & 63;
  const int t  = threadIdx.x;
  const int h  = t >> 5, d = t & 31;

  const float kreg = bf2f(KVh[(size_t)wg * KVD + t]);   // k-half

  for (int p = 0; p < NP2; ++p) {
    const int y = 2 * i + (p >> 2) - 1;
    const int x = 2 * j + (p & 3) - 1;
    float q = 0.f;
    if ((unsigned)y < (unsigned)HB && (unsigned)x < (unsigned)WB)
      q = bf2f(Qh[((size_t)(b * NPIX + y * WB + x)) * DIM + t]);
    float part = q * kreg;
#pragma unroll
    for (int off = 16; off; off >>= 1) part += __shfl_xor(part, off, 32);
    if (d == 0) {
      const float logit = part * SCALE + rel_init[p] + rel_bias[p];
      E[(size_t)wg * 128 + h * NP2 + p] = expf(logit);
    }
  }
}

// ---------------------------------------------------------------------------
// S[b,h,y,x] = fold(E)
// ---------------------------------------------------------------------------
__global__ __launch_bounds__(256) void s_kernel(
    const float* __restrict__ E, float* __restrict__ S)
{
  const int idx = blockIdx.x * 256 + threadIdx.x;
  const int b  = idx >> 17;
  const int r  = idx & 131071;
  const int h  = r >> 14;
  const int yx = r & 16383;
  const int y  = yx >> 7, x = yx & 127;

  const int ilo = max(0, (y - 1) >> 1), ihi = min(HT - 1, (y + 1) >> 1);
  const int jlo = max(0, (x - 1) >> 1), jhi = min(WT - 1, (x + 1) >> 1);

  float s = 0.f;
  for (int i = ilo; i <= ihi; ++i)
    for (int j = jlo; j <= jhi; ++j) {
      const int p = (y + 1 - 2 * i) * 4 + (x + 1 - 2 * j);
      s += E[((size_t)(b * NWIN + i * WT + j)) * 128 + h * NP2 + p];
    }
  S[idx] = s;
}

// ---------------------------------------------------------------------------
// out_pre[b,pix,c] (bf16) = sum over covering windows of (E / s_scrambled) * v.
// Scramble (faithful to the reference reshape): g = w*128+h*16+p;
// h_eff = w>>9; w_eff = (w&511)*8 + h; p_eff = p; padding divisor -> 1.
// ---------------------------------------------------------------------------
__global__ __launch_bounds__(256) void o_kernel(
    const float* __restrict__ E, const float* __restrict__ S,
    const unsigned short* __restrict__ KVh, unsigned short* __restrict__ out_pre)
{
  const int pg = blockIdx.x;          // b*16384 + y*128 + x
  const int b  = pg >> 14;
  const int yx = pg & 16383;
  const int y  = yx >> 7, x = yx & 127;
  const int t  = threadIdx.x;
  const int h  = t >> 5;

  const int ilo = max(0, (y - 1) >> 1), ihi = min(HT - 1, (y + 1) >> 1);
  const int jlo = max(0, (x - 1) >> 1), jhi = min(WT - 1, (x + 1) >> 1);

  float acc = 0.f;
  for (int i = ilo; i <= ihi; ++i)
    for (int j = jlo; j <= jhi; ++j) {
      const int w = i * WT + j;
      const int p = (y + 1 - 2 * i) * 4 + (x + 1 - 2 * j);
      const float e = E[((size_t)(b * NWIN + w)) * 128 + h * NP2 + p];
      const int h_eff = w >> 9;
      const int w_eff = ((w & 511) << 3) + h;
      const int i2 = w_eff >> 6, j2 = w_eff & 63;
      const int y2 = 2 * i2 + (p >> 2) - 1;
      const int x2 = 2 * j2 + (p & 3) - 1;
      float s = 1.f;
      if ((unsigned)y2 < (unsigned)HB && (unsigned)x2 < (unsigned)WB)
        s = S[(size_t)((b * HEADS + h_eff) * NPIX) + y2 * WB + x2];
      const float v = bf2f(KVh[((size_t)(b * NWIN + w)) * KVD + 256 + t]);
      acc = fmaf(e / s, v, acc);
    }
  out_pre[(size_t)pg * DIM + t] = f2bf(acc);
}

// ---------------------------------------------------------------------------
extern "C" void kernel_launch(void* const* d_in, const int* in_sizes, int n_in,
                              void* d_out, int out_size, void* d_ws, size_t ws_size,
                              hipStream_t stream) {
  const float* Xt       = (const float*)d_in[0];  // (4, 4096, 512)
  const float* Xb       = (const float*)d_in[1];  // (4, 16384, 256)
  const float* q_w      = (const float*)d_in[2];  // (256, 256)
  const float* kv_w     = (const float*)d_in[3];  // (512, 512)
  const float* proj_w   = (const float*)d_in[4];  // (256, 256)
  const float* proj_b   = (const float*)d_in[5];  // (256,)
  const float* rel_init = (const float*)d_in[6];  // (16,)
  const float* rel_bias = (const float*)d_in[7];  // (16,)
  float* out = (float*)d_out;                     // (4, 16384, 256)

  char* ws = (char*)d_ws;
  const size_t nXb = (size_t)B_ * NPIX * DIM;     // 16.78M
  const size_t nXt = (size_t)B_ * NWIN * KVD;     // 8.39M
  const size_t nQW = (size_t)DIM * DIM;           // 65536
  const size_t nKVW = (size_t)KVD * KVD;          // 262144
  unsigned short* Xbh  = (unsigned short*)ws;                 ws += nXb * 2;   // 32 MB (reused as Oh)
  unsigned short* Xth  = (unsigned short*)ws;                 ws += nXt * 2;   // 16 MB
  unsigned short* Qh   = (unsigned short*)ws;                 ws += nXb * 2;   // 32 MB
  unsigned short* KVh  = (unsigned short*)ws;                 ws += nXt * 2;   // 16 MB
  float*          E    = (float*)ws;                          ws += (size_t)B_ * NWIN * 128 * 4; // 8 MB
  float*          S    = (float*)ws;                          ws += (size_t)B_ * HEADS * NPIX * 4; // 2 MB
  unsigned short* qwh  = (unsigned short*)ws;                 ws += nQW * 2;
  unsigned short* kvwh = (unsigned short*)ws;                 ws += nKVW * 2;
  unsigned short* pwh  = (unsigned short*)ws;                 ws += nQW * 2;
  unsigned short* Oh   = Xbh;   // alias: Xbh dead after GEMM1

  const dim3 blk(256);

  // 0) fp32 -> bf16 casts
  cast_bf16<<<dim3((int)(nXb / 1024)), blk, 0, stream>>>(Xb, Xbh, (int)(nXb / 4));
  cast_bf16<<<dim3((int)(nXt / 1024)), blk, 0, stream>>>(Xt, Xth, (int)(nXt / 4));
  cast_bf16<<<dim3((int)(nQW / 1024)), blk, 0, stream>>>(q_w, qwh, (int)(nQW / 4));
  cast_bf16<<<dim3((int)(nKVW / 1024)), blk, 0, stream>>>(kv_w, kvwh, (int)(nKVW / 4));
  cast_bf16<<<dim3((int)(nQW / 1024)), blk, 0, stream>>>(proj_w, pwh, (int)(nQW / 4));

  // 1) Qh = Xb @ q_w^T   (65536 x 256 x 256), bf16 out
  gemm_bf16<true, false><<<dim3(B_ * NPIX / 128, DIM / 128), blk, 0, stream>>>(
      Xbh, qwh, nullptr, Qh, B_ * NPIX, DIM, DIM);

  // 2) KVh = Xt @ kv_w^T (16384 x 512 x 512), bf16 out
  gemm_bf16<true, false><<<dim3(B_ * NWIN / 128, KVD / 128), blk, 0, stream>>>(
      Xth, kvwh, nullptr, KVh, B_ * NWIN, KVD, KVD);

  // 3) E = exp(scale*qk + rel)
  e_kernel<<<dim3(B_ * NWIN), blk, 0, stream>>>(Qh, KVh, rel_init, rel_bias, E);

  // 4) S = fold(E)
  s_kernel<<<dim3(B_ * HEADS * NPIX / 256), blk, 0, stream>>>(E, S);

  // 5) Oh = fold((E/s_scrambled) * v)  [bf16, into Xbh buffer]
  o_kernel<<<dim3(B_ * NPIX), blk, 0, stream>>>(E, S, KVh, Oh);

  // 6) out = Oh @ proj_w^T + proj_b   (fp32 out)
  gemm_bf16<false, true><<<dim3(B_ * NPIX / 128, DIM / 128), blk, 0, stream>>>(
      Oh, pwh, proj_b, out, B_ * NPIX, DIM, DIM);
}

// Round 3
// 277.979 us; speedup vs baseline: 2.2487x; 1.3951x over previous
//
#include <hip/hip_runtime.h>
#include <math.h>

// ---------------------------------------------------------------------------
// InterLevelAttention, MI355X. Fixed shapes from setup_inputs().
// Round 3: restructured e/o kernels (per-thread serial dot, 8ch/thread gather),
// R = E/S_scrambled hoisted out of the o-gather.
// ---------------------------------------------------------------------------
constexpr int B_    = 4;
constexpr int HT    = 64,  WT = 64;
constexpr int HB    = 128, WB = 128;
constexpr int DIM   = 256;           // attn dim
constexpr int KVD   = 512;           // kv_dim (k|v concatenated after proj)
constexpr int HEADS = 8;
constexpr int NP2   = 16;            // 4x4 window
constexpr int NPIX  = HB * WB;       // 16384 fine pixels / batch
constexpr int NWIN  = HT * WT;       // 4096 windows / batch
constexpr float SCALE = 0.17677669529663687f;  // 32^-0.5

using bf16x8 = __attribute__((ext_vector_type(8))) short;
using f32x4  = __attribute__((ext_vector_type(4))) float;

__device__ __forceinline__ unsigned short f2bf(float f) {
  union { float f; unsigned u; } v; v.f = f;
  unsigned r = v.u + 0x7fffu + ((v.u >> 16) & 1u);   // RNE
  return (unsigned short)(r >> 16);
}

// ---------------------------------------------------------------------------
// fp32 -> bf16 cast, 4 elems/thread. n4 = n/4.
// ---------------------------------------------------------------------------
__global__ __launch_bounds__(256) void cast_bf16(
    const float* __restrict__ in, unsigned short* __restrict__ out, int n4)
{
  const int i = blockIdx.x * 256 + threadIdx.x;
  if (i >= n4) return;
  float4 v = ((const float4*)in)[i];
  ushort4 o;
  o.x = f2bf(v.x); o.y = f2bf(v.y); o.z = f2bf(v.z); o.w = f2bf(v.w);
  ((ushort4*)out)[i] = o;
}

// ---------------------------------------------------------------------------
// bf16 MFMA GEMM: C[M,N] = A[M,K] @ Bw[N,K]^T (+bias), 128x128 tile, BK=32,
// 256 threads = 4 waves (2x2), 16x16x32 MFMA, global_load_lds width 16.
// ---------------------------------------------------------------------------
template<bool BF16_OUT, bool BIAS>
__global__ __launch_bounds__(256) void gemm_bf16(
    const unsigned short* __restrict__ A, const unsigned short* __restrict__ Bw,
    const float* __restrict__ bias, void* __restrict__ C,
    int M, int N, int K)
{
  __shared__ unsigned short Ash[128 * 32];
  __shared__ unsigned short Bsh[128 * 32];

  const int tid  = threadIdx.x;
  const int wave = tid >> 6;
  const int lane = tid & 63;
  const int m0 = blockIdx.x * 128;
  const int n0 = blockIdx.y * 128;
  const int wm = (wave >> 1) * 64;
  const int wn = (wave & 1) * 64;

  const int c0 = wave * 64 + lane;
  const int c1 = 256 + c0;
  const int r0 = c0 >> 2, k0off = (c0 & 3) * 8;
  const int r1 = c1 >> 2, k1off = (c1 & 3) * 8;
  const int ldsOff0 = wave * 1024;
  const int ldsOff1 = 4096 + wave * 1024;

  f32x4 acc[4][4];
#pragma unroll
  for (int i = 0; i < 4; ++i)
#pragma unroll
    for (int j = 0; j < 4; ++j) { f32x4 z = {0.f, 0.f, 0.f, 0.f}; acc[i][j] = z; }

  const int fr = lane & 15;
  const int fk = (lane >> 4) * 8;

  for (int kk = 0; kk < K; kk += 32) {
    __syncthreads();
    const unsigned short* a0 = A  + (size_t)(m0 + r0) * K + kk + k0off;
    const unsigned short* a1 = A  + (size_t)(m0 + r1) * K + kk + k1off;
    const unsigned short* b0 = Bw + (size_t)(n0 + r0) * K + kk + k0off;
    const unsigned short* b1 = Bw + (size_t)(n0 + r1) * K + kk + k1off;
    __builtin_amdgcn_global_load_lds(
        (const __attribute__((address_space(1))) unsigned int*)a0,
        (__attribute__((address_space(3))) unsigned int*)((char*)Ash + ldsOff0),
        16, 0, 0);
    __builtin_amdgcn_global_load_lds(
        (const __attribute__((address_space(1))) unsigned int*)a1,
        (__attribute__((address_space(3))) unsigned int*)((char*)Ash + ldsOff1),
        16, 0, 0);
    __builtin_amdgcn_global_load_lds(
        (const __attribute__((address_space(1))) unsigned int*)b0,
        (__attribute__((address_space(3))) unsigned int*)((char*)Bsh + ldsOff0),
        16, 0, 0);
    __builtin_amdgcn_global_load_lds(
        (const __attribute__((address_space(1))) unsigned int*)b1,
        (__attribute__((address_space(3))) unsigned int*)((char*)Bsh + ldsOff1),
        16, 0, 0);
    __syncthreads();

    bf16x8 af[4], bfr[4];
#pragma unroll
    for (int t = 0; t < 4; ++t) {
      af[t]  = *(const bf16x8*)&Ash[(wm + t * 16 + fr) * 32 + fk];
      bfr[t] = *(const bf16x8*)&Bsh[(wn + t * 16 + fr) * 32 + fk];
    }
#pragma unroll
    for (int mt = 0; mt < 4; ++mt)
#pragma unroll
      for (int nt = 0; nt < 4; ++nt)
        acc[mt][nt] = __builtin_amdgcn_mfma_f32_16x16x32_bf16(
            af[mt], bfr[nt], acc[mt][nt], 0, 0, 0);
  }

  const int col0 = lane & 15;
  const int rb   = (lane >> 4) * 4;
#pragma unroll
  for (int mt = 0; mt < 4; ++mt) {
#pragma unroll
    for (int nt = 0; nt < 4; ++nt) {
      const int col = n0 + wn + nt * 16 + col0;
      float bv = BIAS ? bias[col] : 0.f;
#pragma unroll
      for (int r = 0; r < 4; ++r) {
        const int row = m0 + wm + mt * 16 + rb + r;
        const float v = acc[mt][nt][r] + bv;
        if (BF16_OUT) ((unsigned short*)C)[(size_t)row * N + col] = f2bf(v);
        else          ((float*)C)[(size_t)row * N + col] = v;
      }
    }
  }
}

// ---------------------------------------------------------------------------
// E[bw, h, p] = exp(scale*<q(pixel(w,p),h), k(bw,h)> + rel_init[p]+rel_bias[p])
// One thread per (wg,h,p): serial 32-elem dot, 4x uint4 loads each side.
// Block = 256 threads = 2 windows.
// ---------------------------------------------------------------------------
__global__ __launch_bounds__(256) void e_kernel(
    const unsigned short* __restrict__ Qh, const unsigned short* __restrict__ KVh,
    const float* __restrict__ rel_init, const float* __restrict__ rel_bias,
    float* __restrict__ E)
{
  const int t   = threadIdx.x;
  const int wg  = blockIdx.x * 2 + (t >> 7);   // b*4096 + w
  const int lcl = t & 127;
  const int h   = lcl >> 4, p = lcl & 15;
  const int b = wg >> 12, w = wg & 4095;
  const int i = w >> 6, j = w & 63;
  const int y = 2 * i + (p >> 2) - 1;
  const int x = 2 * j + (p & 3) - 1;

  const uint4* kp = (const uint4*)(KVh + (size_t)wg * KVD + h * 32);
  uint4 kv0 = kp[0], kv1 = kp[1], kv2 = kp[2], kv3 = kp[3];

  uint4 qv0 = {0,0,0,0}, qv1 = {0,0,0,0}, qv2 = {0,0,0,0}, qv3 = {0,0,0,0};
  if ((unsigned)y < (unsigned)HB && (unsigned)x < (unsigned)WB) {
    const uint4* qp = (const uint4*)(Qh + ((size_t)(b * NPIX + y * WB + x)) * DIM + h * 32);
    qv0 = qp[0]; qv1 = qp[1]; qv2 = qp[2]; qv3 = qp[3];
  }

  float acc = 0.f;
  const unsigned qa[16] = {qv0.x,qv0.y,qv0.z,qv0.w, qv1.x,qv1.y,qv1.z,qv1.w,
                           qv2.x,qv2.y,qv2.z,qv2.w, qv3.x,qv3.y,qv3.z,qv3.w};
  const unsigned ka[16] = {kv0.x,kv0.y,kv0.z,kv0.w, kv1.x,kv1.y,kv1.z,kv1.w,
                           kv2.x,kv2.y,kv2.z,kv2.w, kv3.x,kv3.y,kv3.z,kv3.w};
#pragma unroll
  for (int q = 0; q < 16; ++q) {
    acc = fmaf(__uint_as_float(qa[q] << 16),
               __uint_as_float(ka[q] << 16), acc);
    acc = fmaf(__uint_as_float(qa[q] & 0xffff0000u),
               __uint_as_float(ka[q] & 0xffff0000u), acc);
  }
  E[(size_t)wg * 128 + h * NP2 + p] = expf(acc * SCALE + rel_init[p] + rel_bias[p]);
}

// ---------------------------------------------------------------------------
// S[b,h,y,x] = fold(E)
// ---------------------------------------------------------------------------
__global__ __launch_bounds__(256) void s_kernel(
    const float* __restrict__ E, float* __restrict__ S)
{
  const int idx = blockIdx.x * 256 + threadIdx.x;
  const int b  = idx >> 17;
  const int r  = idx & 131071;
  const int h  = r >> 14;
  const int yx = r & 16383;
  const int y  = yx >> 7, x = yx & 127;

  const int ilo = max(0, (y - 1) >> 1), ihi = min(HT - 1, (y + 1) >> 1);
  const int jlo = max(0, (x - 1) >> 1), jhi = min(WT - 1, (x + 1) >> 1);

  float s = 0.f;
  for (int i = ilo; i <= ihi; ++i)
    for (int j = jlo; j <= jhi; ++j) {
      const int p = (y + 1 - 2 * i) * 4 + (x + 1 - 2 * j);
      s += E[((size_t)(b * NWIN + i * WT + j)) * 128 + h * NP2 + p];
    }
  S[idx] = s;
}

// ---------------------------------------------------------------------------
// R[b,w,h,p] = E[b,w,h,p] / S_scrambled. Scramble (faithful to reference
// reshape quirk): h_eff = w>>9; w_eff = (w&511)*8 + h; p_eff = p;
// padding divisor -> 1.
// ---------------------------------------------------------------------------
__global__ __launch_bounds__(256) void r_kernel(
    const float* __restrict__ E, const float* __restrict__ S,
    float* __restrict__ R)
{
  const int idx = blockIdx.x * 256 + threadIdx.x;   // b*2^19 + w*128 + h*16 + p
  const int b  = idx >> 19;
  const int r  = idx & 524287;
  const int w  = r >> 7;
  const int t7 = r & 127;
  const int h  = t7 >> 4, p = t7 & 15;

  const int h_eff = w >> 9;
  const int w_eff = ((w & 511) << 3) + h;
  const int i2 = w_eff >> 6, j2 = w_eff & 63;
  const int y2 = 2 * i2 + (p >> 2) - 1;
  const int x2 = 2 * j2 + (p & 3) - 1;
  float s = 1.f;
  if ((unsigned)y2 < (unsigned)HB && (unsigned)x2 < (unsigned)WB)
    s = S[(size_t)((b * HEADS + h_eff) * NPIX) + y2 * WB + x2];
  R[idx] = E[idx] / s;
}

// ---------------------------------------------------------------------------
// out_pre[b,pix,c] (bf16) = sum over covering windows of R * v.
// 8 channels/thread (uint4 v load), 32 threads/pixel, 8 pixels/block.
// ---------------------------------------------------------------------------
__global__ __launch_bounds__(256) void o_kernel(
    const float* __restrict__ R, const unsigned short* __restrict__ KVh,
    unsigned short* __restrict__ out_pre)
{
  const int t  = threadIdx.x;
  const int pg = blockIdx.x * 8 + (t >> 5);   // b*16384 + y*128 + x
  const int b  = pg >> 14;
  const int yx = pg & 16383;
  const int y  = yx >> 7, x = yx & 127;
  const int c8 = t & 31;                      // channels c8*8 .. c8*8+7
  const int h  = c8 >> 2;

  const int ilo = max(0, (y - 1) >> 1), ihi = min(HT - 1, (y + 1) >> 1);
  const int jlo = max(0, (x - 1) >> 1), jhi = min(WT - 1, (x + 1) >> 1);

  float acc[8] = {};
  for (int i = ilo; i <= ihi; ++i)
    for (int j = jlo; j <= jhi; ++j) {
      const int w = i * WT + j;
      const int p = (y + 1 - 2 * i) * 4 + (x + 1 - 2 * j);
      const float rr = R[((size_t)(b * NWIN + w)) * 128 + h * NP2 + p];
      const uint4 v = *(const uint4*)(KVh + ((size_t)(b * NWIN + w)) * KVD + 256 + c8 * 8);
      const unsigned vv[4] = {v.x, v.y, v.z, v.w};
#pragma unroll
      for (int q = 0; q < 4; ++q) {
        acc[2*q]   = fmaf(rr, __uint_as_float(vv[q] << 16),        acc[2*q]);
        acc[2*q+1] = fmaf(rr, __uint_as_float(vv[q] & 0xffff0000u), acc[2*q+1]);
      }
    }

  uint4 ov;
  ov.x = (unsigned)f2bf(acc[0]) | ((unsigned)f2bf(acc[1]) << 16);
  ov.y = (unsigned)f2bf(acc[2]) | ((unsigned)f2bf(acc[3]) << 16);
  ov.z = (unsigned)f2bf(acc[4]) | ((unsigned)f2bf(acc[5]) << 16);
  ov.w = (unsigned)f2bf(acc[6]) | ((unsigned)f2bf(acc[7]) << 16);
  *(uint4*)(out_pre + (size_t)pg * DIM + c8 * 8) = ov;
}

// ---------------------------------------------------------------------------
extern "C" void kernel_launch(void* const* d_in, const int* in_sizes, int n_in,
                              void* d_out, int out_size, void* d_ws, size_t ws_size,
                              hipStream_t stream) {
  const float* Xt       = (const float*)d_in[0];  // (4, 4096, 512)
  const float* Xb       = (const float*)d_in[1];  // (4, 16384, 256)
  const float* q_w      = (const float*)d_in[2];  // (256, 256)
  const float* kv_w     = (const float*)d_in[3];  // (512, 512)
  const float* proj_w   = (const float*)d_in[4];  // (256, 256)
  const float* proj_b   = (const float*)d_in[5];  // (256,)
  const float* rel_init = (const float*)d_in[6];  // (16,)
  const float* rel_bias = (const float*)d_in[7];  // (16,)
  float* out = (float*)d_out;                     // (4, 16384, 256)

  char* ws = (char*)d_ws;
  const size_t nXb = (size_t)B_ * NPIX * DIM;     // 16.78M
  const size_t nXt = (size_t)B_ * NWIN * KVD;     // 8.39M
  const size_t nQW = (size_t)DIM * DIM;
  const size_t nKVW = (size_t)KVD * KVD;
  unsigned short* Xbh  = (unsigned short*)ws;  ws += nXb * 2;   // 32 MB (reused as Oh)
  unsigned short* Xth  = (unsigned short*)ws;  ws += nXt * 2;   // 16 MB (reused as R)
  unsigned short* Qh   = (unsigned short*)ws;  ws += nXb * 2;   // 32 MB
  unsigned short* KVh  = (unsigned short*)ws;  ws += nXt * 2;   // 16 MB
  float*          E    = (float*)ws;           ws += (size_t)B_ * NWIN * 128 * 4;   // 8 MB
  float*          S    = (float*)ws;           ws += (size_t)B_ * HEADS * NPIX * 4; // 2 MB
  unsigned short* qwh  = (unsigned short*)ws;  ws += nQW * 2;
  unsigned short* kvwh = (unsigned short*)ws;  ws += nKVW * 2;
  unsigned short* pwh  = (unsigned short*)ws;  ws += nQW * 2;
  unsigned short* Oh   = Xbh;        // alias: Xbh dead after GEMM1
  float*          R    = (float*)Xth; // alias: Xth dead after GEMM2 (8 MB < 16 MB)

  const dim3 blk(256);

  // 0) fp32 -> bf16 casts
  cast_bf16<<<dim3((int)(nXb / 1024)), blk, 0, stream>>>(Xb, Xbh, (int)(nXb / 4));
  cast_bf16<<<dim3((int)(nXt / 1024)), blk, 0, stream>>>(Xt, Xth, (int)(nXt / 4));
  cast_bf16<<<dim3((int)(nQW / 1024)), blk, 0, stream>>>(q_w, qwh, (int)(nQW / 4));
  cast_bf16<<<dim3((int)(nKVW / 1024)), blk, 0, stream>>>(kv_w, kvwh, (int)(nKVW / 4));
  cast_bf16<<<dim3((int)(nQW / 1024)), blk, 0, stream>>>(proj_w, pwh, (int)(nQW / 4));

  // 1) Qh = Xb @ q_w^T   (65536 x 256 x 256), bf16 out
  gemm_bf16<true, false><<<dim3(B_ * NPIX / 128, DIM / 128), blk, 0, stream>>>(
      Xbh, qwh, nullptr, Qh, B_ * NPIX, DIM, DIM);

  // 2) KVh = Xt @ kv_w^T (16384 x 512 x 512), bf16 out
  gemm_bf16<true, false><<<dim3(B_ * NWIN / 128, KVD / 128), blk, 0, stream>>>(
      Xth, kvwh, nullptr, KVh, B_ * NWIN, KVD, KVD);

  // 3) E = exp(scale*qk + rel)
  e_kernel<<<dim3(B_ * NWIN / 2), blk, 0, stream>>>(Qh, KVh, rel_init, rel_bias, E);

  // 4) S = fold(E)
  s_kernel<<<dim3(B_ * HEADS * NPIX / 256), blk, 0, stream>>>(E, S);

  // 5) R = E / S_scrambled   [into Xth buffer]
  r_kernel<<<dim3(B_ * NWIN * 128 / 256), blk, 0, stream>>>(E, S, R);

  // 6) Oh = fold(R * v)  [bf16, into Xbh buffer]
  o_kernel<<<dim3(B_ * NPIX / 8), blk, 0, stream>>>(R, KVh, Oh);

  // 7) out = Oh @ proj_w^T + proj_b   (fp32 out)
  gemm_bf16<false, true><<<dim3(B_ * NPIX / 128, DIM / 128), blk, 0, stream>>>(
      Oh, pwh, proj_b, out, B_ * NPIX, DIM, DIM);
}

// Round 4
// 262.042 us; speedup vs baseline: 2.3855x; 1.0608x over previous
//
#include <hip/hip_runtime.h>
#include <math.h>

// ---------------------------------------------------------------------------
// InterLevelAttention, MI355X. Fixed shapes from setup_inputs().
// Round 4: fused-cast GEMM1 (fp32 A staging), e+s fusion (per-pixel q reuse),
// merged cast kernel, 13 -> 7 launches, ws aliasing.
// ---------------------------------------------------------------------------
constexpr int B_    = 4;
constexpr int HT    = 64,  WT = 64;
constexpr int HB    = 128, WB = 128;
constexpr int DIM   = 256;
constexpr int KVD   = 512;
constexpr int HEADS = 8;
constexpr int NP2   = 16;
constexpr int NPIX  = HB * WB;       // 16384
constexpr int NWIN  = HT * WT;       // 4096
constexpr float SCALE = 0.17677669529663687f;  // 32^-0.5

using bf16x8 = __attribute__((ext_vector_type(8))) short;
using f32x4  = __attribute__((ext_vector_type(4))) float;

__device__ __forceinline__ unsigned short f2bf(float f) {
  union { float f; unsigned u; } v; v.f = f;
  unsigned r = v.u + 0x7fffu + ((v.u >> 16) & 1u);   // RNE
  return (unsigned short)(r >> 16);
}

// ---------------------------------------------------------------------------
// Merged fp32->bf16 cast: Xt + q_w + kv_w + proj_w in one launch.
// float4 per thread; segment chosen by flat float4 index.
// ---------------------------------------------------------------------------
constexpr int NXT4  = B_ * NWIN * KVD / 4;   // 2,097,152
constexpr int NQW4  = DIM * DIM / 4;         // 16,384
constexpr int NKVW4 = KVD * KVD / 4;         // 65,536
constexpr int NCAST4 = NXT4 + NQW4 + NKVW4 + NQW4;  // 2,195,456 (grid*256 exact)

__global__ __launch_bounds__(256) void cast_all(
    const float* __restrict__ Xt, const float* __restrict__ qw,
    const float* __restrict__ kvw, const float* __restrict__ pw,
    unsigned short* __restrict__ Xth, unsigned short* __restrict__ qwh,
    unsigned short* __restrict__ kvwh, unsigned short* __restrict__ pwh)
{
  const int i = blockIdx.x * 256 + threadIdx.x;
  const float* src; unsigned short* dst; int off;
  if (i < NXT4)                     { src = Xt;  dst = Xth;  off = i; }
  else if (i < NXT4 + NQW4)         { src = qw;  dst = qwh;  off = i - NXT4; }
  else if (i < NXT4 + NQW4 + NKVW4) { src = kvw; dst = kvwh; off = i - NXT4 - NQW4; }
  else                              { src = pw;  dst = pwh;  off = i - NXT4 - NQW4 - NKVW4; }
  float4 v = ((const float4*)src)[off];
  ushort4 o;
  o.x = f2bf(v.x); o.y = f2bf(v.y); o.z = f2bf(v.z); o.w = f2bf(v.w);
  ((ushort4*)dst)[off] = o;
}

// ---------------------------------------------------------------------------
// GEMM1: C[M,N](bf16) = A[M,K](fp32, converted in staging) @ Bw[N,K](bf16)^T
// 128x128 tile, BK=32, 256 thr = 4 waves, 16x16x32 MFMA.
// A: float4 loads + cvt + ds_write_b64; B: global_load_lds w=16.
// ---------------------------------------------------------------------------
__global__ __launch_bounds__(256) void gemm_af32(
    const float* __restrict__ A, const unsigned short* __restrict__ Bw,
    unsigned short* __restrict__ C, int M, int N, int K)
{
  __shared__ unsigned short Ash[128 * 32];
  __shared__ unsigned short Bsh[128 * 32];

  const int tid  = threadIdx.x;
  const int wave = tid >> 6;
  const int lane = tid & 63;
  const int m0 = blockIdx.x * 128;
  const int n0 = blockIdx.y * 128;
  const int wm = (wave >> 1) * 64;
  const int wn = (wave & 1) * 64;

  // B staging (global_load_lds, 2 issues of 256 x 16B chunks)
  const int c0 = wave * 64 + lane;
  const int c1 = 256 + c0;
  const int r0 = c0 >> 2, k0off = (c0 & 3) * 8;
  const int r1 = c1 >> 2, k1off = (c1 & 3) * 8;
  const int ldsOff0 = wave * 1024;
  const int ldsOff1 = 4096 + wave * 1024;

  f32x4 acc[4][4];
#pragma unroll
  for (int i = 0; i < 4; ++i)
#pragma unroll
    for (int j = 0; j < 4; ++j) { f32x4 z = {0.f, 0.f, 0.f, 0.f}; acc[i][j] = z; }

  const int fr = lane & 15;
  const int fk = (lane >> 4) * 8;

  for (int kk = 0; kk < K; kk += 32) {
    __syncthreads();
    // A: 128 rows x 32 k fp32 -> bf16. chunk c (4 fp32): row=c>>3, kq=(c&7)*4.
#pragma unroll
    for (int u = 0; u < 4; ++u) {
      const int c   = tid + u * 256;
      const int row = c >> 3;
      const int kq  = (c & 7) * 4;
      float4 v = *(const float4*)(A + (size_t)(m0 + row) * K + kk + kq);
      uint2 pk;
      pk.x = (unsigned)f2bf(v.x) | ((unsigned)f2bf(v.y) << 16);
      pk.y = (unsigned)f2bf(v.z) | ((unsigned)f2bf(v.w) << 16);
      *(uint2*)&Ash[row * 32 + kq] = pk;
    }
    const unsigned short* b0 = Bw + (size_t)(n0 + r0) * K + kk + k0off;
    const unsigned short* b1 = Bw + (size_t)(n0 + r1) * K + kk + k1off;
    __builtin_amdgcn_global_load_lds(
        (const __attribute__((address_space(1))) unsigned int*)b0,
        (__attribute__((address_space(3))) unsigned int*)((char*)Bsh + ldsOff0),
        16, 0, 0);
    __builtin_amdgcn_global_load_lds(
        (const __attribute__((address_space(1))) unsigned int*)b1,
        (__attribute__((address_space(3))) unsigned int*)((char*)Bsh + ldsOff1),
        16, 0, 0);
    __syncthreads();

    bf16x8 af[4], bfr[4];
#pragma unroll
    for (int t = 0; t < 4; ++t) {
      af[t]  = *(const bf16x8*)&Ash[(wm + t * 16 + fr) * 32 + fk];
      bfr[t] = *(const bf16x8*)&Bsh[(wn + t * 16 + fr) * 32 + fk];
    }
#pragma unroll
    for (int mt = 0; mt < 4; ++mt)
#pragma unroll
      for (int nt = 0; nt < 4; ++nt)
        acc[mt][nt] = __builtin_amdgcn_mfma_f32_16x16x32_bf16(
            af[mt], bfr[nt], acc[mt][nt], 0, 0, 0);
  }

  const int col0 = lane & 15;
  const int rb   = (lane >> 4) * 4;
#pragma unroll
  for (int mt = 0; mt < 4; ++mt)
#pragma unroll
    for (int nt = 0; nt < 4; ++nt) {
      const int col = n0 + wn + nt * 16 + col0;
#pragma unroll
      for (int r = 0; r < 4; ++r) {
        const int row = m0 + wm + mt * 16 + rb + r;
        C[(size_t)row * N + col] = f2bf(acc[mt][nt][r]);
      }
    }
}

// ---------------------------------------------------------------------------
// bf16 MFMA GEMM (both operands bf16): GEMM2 (KV proj) and GEMM3 (out proj).
// ---------------------------------------------------------------------------
template<bool BF16_OUT, bool BIAS>
__global__ __launch_bounds__(256) void gemm_bf16(
    const unsigned short* __restrict__ A, const unsigned short* __restrict__ Bw,
    const float* __restrict__ bias, void* __restrict__ C,
    int M, int N, int K)
{
  __shared__ unsigned short Ash[128 * 32];
  __shared__ unsigned short Bsh[128 * 32];

  const int tid  = threadIdx.x;
  const int wave = tid >> 6;
  const int lane = tid & 63;
  const int m0 = blockIdx.x * 128;
  const int n0 = blockIdx.y * 128;
  const int wm = (wave >> 1) * 64;
  const int wn = (wave & 1) * 64;

  const int c0 = wave * 64 + lane;
  const int c1 = 256 + c0;
  const int r0 = c0 >> 2, k0off = (c0 & 3) * 8;
  const int r1 = c1 >> 2, k1off = (c1 & 3) * 8;
  const int ldsOff0 = wave * 1024;
  const int ldsOff1 = 4096 + wave * 1024;

  f32x4 acc[4][4];
#pragma unroll
  for (int i = 0; i < 4; ++i)
#pragma unroll
    for (int j = 0; j < 4; ++j) { f32x4 z = {0.f, 0.f, 0.f, 0.f}; acc[i][j] = z; }

  const int fr = lane & 15;
  const int fk = (lane >> 4) * 8;

  for (int kk = 0; kk < K; kk += 32) {
    __syncthreads();
    const unsigned short* a0 = A  + (size_t)(m0 + r0) * K + kk + k0off;
    const unsigned short* a1 = A  + (size_t)(m0 + r1) * K + kk + k1off;
    const unsigned short* b0 = Bw + (size_t)(n0 + r0) * K + kk + k0off;
    const unsigned short* b1 = Bw + (size_t)(n0 + r1) * K + kk + k1off;
    __builtin_amdgcn_global_load_lds(
        (const __attribute__((address_space(1))) unsigned int*)a0,
        (__attribute__((address_space(3))) unsigned int*)((char*)Ash + ldsOff0),
        16, 0, 0);
    __builtin_amdgcn_global_load_lds(
        (const __attribute__((address_space(1))) unsigned int*)a1,
        (__attribute__((address_space(3))) unsigned int*)((char*)Ash + ldsOff1),
        16, 0, 0);
    __builtin_amdgcn_global_load_lds(
        (const __attribute__((address_space(1))) unsigned int*)b0,
        (__attribute__((address_space(3))) unsigned int*)((char*)Bsh + ldsOff0),
        16, 0, 0);
    __builtin_amdgcn_global_load_lds(
        (const __attribute__((address_space(1))) unsigned int*)b1,
        (__attribute__((address_space(3))) unsigned int*)((char*)Bsh + ldsOff1),
        16, 0, 0);
    __syncthreads();

    bf16x8 af[4], bfr[4];
#pragma unroll
    for (int t = 0; t < 4; ++t) {
      af[t]  = *(const bf16x8*)&Ash[(wm + t * 16 + fr) * 32 + fk];
      bfr[t] = *(const bf16x8*)&Bsh[(wn + t * 16 + fr) * 32 + fk];
    }
#pragma unroll
    for (int mt = 0; mt < 4; ++mt)
#pragma unroll
      for (int nt = 0; nt < 4; ++nt)
        acc[mt][nt] = __builtin_amdgcn_mfma_f32_16x16x32_bf16(
            af[mt], bfr[nt], acc[mt][nt], 0, 0, 0);
  }

  const int col0 = lane & 15;
  const int rb   = (lane >> 4) * 4;
#pragma unroll
  for (int mt = 0; mt < 4; ++mt)
#pragma unroll
    for (int nt = 0; nt < 4; ++nt) {
      const int col = n0 + wn + nt * 16 + col0;
      float bv = BIAS ? bias[col] : 0.f;
#pragma unroll
      for (int r = 0; r < 4; ++r) {
        const int row = m0 + wm + mt * 16 + rb + r;
        const float v = acc[mt][nt][r] + bv;
        if (BF16_OUT) ((unsigned short*)C)[(size_t)row * N + col] = f2bf(v);
        else          ((float*)C)[(size_t)row * N + col] = v;
      }
    }
}

// ---------------------------------------------------------------------------
// Fused e+s: one thread per (b, pixel, h). Loads q(pixel,h) ONCE, iterates
// the <=4 covering windows, computes E contributions and the folded sum S.
// E slots for padding (window,pos) pairs stay unwritten (only ever consumed
// by r_kernel's divide, whose result o_kernel never reads -> safe).
// ---------------------------------------------------------------------------
__global__ __launch_bounds__(256) void es_kernel(
    const unsigned short* __restrict__ Qh, const unsigned short* __restrict__ KVh,
    const float* __restrict__ rel_init, const float* __restrict__ rel_bias,
    float* __restrict__ E, float* __restrict__ S)
{
  const int idx = blockIdx.x * 256 + threadIdx.x;
  const int h = idx & 7;
  const int x = (idx >> 3) & 127;
  const int y = (idx >> 10) & 127;
  const int b = idx >> 17;

  const uint4* qp = (const uint4*)(Qh + ((size_t)((b << 14) + y * WB + x)) * DIM + h * 32);
  uint4 q0 = qp[0], q1 = qp[1], q2 = qp[2], q3 = qp[3];
  const unsigned qa[16] = {q0.x,q0.y,q0.z,q0.w, q1.x,q1.y,q1.z,q1.w,
                           q2.x,q2.y,q2.z,q2.w, q3.x,q3.y,q3.z,q3.w};

  const int ilo = max(0, (y - 1) >> 1), ihi = min(HT - 1, (y + 1) >> 1);
  const int jlo = max(0, (x - 1) >> 1), jhi = min(WT - 1, (x + 1) >> 1);

  float s = 0.f;
  for (int i = ilo; i <= ihi; ++i)
    for (int j = jlo; j <= jhi; ++j) {
      const int w = i * WT + j;
      const int p = (y + 1 - 2 * i) * 4 + (x + 1 - 2 * j);
      const uint4* kp = (const uint4*)(KVh + ((size_t)((b << 12) + w)) * KVD + h * 32);
      uint4 k0 = kp[0], k1 = kp[1], k2 = kp[2], k3 = kp[3];
      const unsigned ka[16] = {k0.x,k0.y,k0.z,k0.w, k1.x,k1.y,k1.z,k1.w,
                               k2.x,k2.y,k2.z,k2.w, k3.x,k3.y,k3.z,k3.w};
      float acc = 0.f;
#pragma unroll
      for (int q = 0; q < 16; ++q) {
        acc = fmaf(__uint_as_float(qa[q] << 16),
                   __uint_as_float(ka[q] << 16), acc);
        acc = fmaf(__uint_as_float(qa[q] & 0xffff0000u),
                   __uint_as_float(ka[q] & 0xffff0000u), acc);
      }
      const float e = expf(acc * SCALE + rel_init[p] + rel_bias[p]);
      E[((size_t)((b << 12) + w)) * 128 + h * NP2 + p] = e;
      s += e;
    }
  S[(size_t)((b * HEADS + h) << 14) + y * WB + x] = s;
}

// ---------------------------------------------------------------------------
// R[b,w,h,p] = E / S_scrambled. Scramble (faithful to reference reshape):
// h_eff = w>>9; w_eff = (w&511)*8 + h; p_eff = p; padding divisor -> 1.
// ---------------------------------------------------------------------------
__global__ __launch_bounds__(256) void r_kernel(
    const float* __restrict__ E, const float* __restrict__ S,
    float* __restrict__ R)
{
  const int idx = blockIdx.x * 256 + threadIdx.x;   // b*2^19 + w*128 + h*16 + p
  const int b  = idx >> 19;
  const int r  = idx & 524287;
  const int w  = r >> 7;
  const int t7 = r & 127;
  const int h  = t7 >> 4, p = t7 & 15;

  const int h_eff = w >> 9;
  const int w_eff = ((w & 511) << 3) + h;
  const int i2 = w_eff >> 6, j2 = w_eff & 63;
  const int y2 = 2 * i2 + (p >> 2) - 1;
  const int x2 = 2 * j2 + (p & 3) - 1;
  float s = 1.f;
  if ((unsigned)y2 < (unsigned)HB && (unsigned)x2 < (unsigned)WB)
    s = S[(size_t)((b * HEADS + h_eff) * NPIX) + y2 * WB + x2];
  R[idx] = E[idx] / s;
}

// ---------------------------------------------------------------------------
// out_pre[b,pix,c] (bf16) = sum over covering windows of R * v.
// 8 channels/thread (uint4 v load), 32 threads/pixel, 8 pixels/block.
// ---------------------------------------------------------------------------
__global__ __launch_bounds__(256) void o_kernel(
    const float* __restrict__ R, const unsigned short* __restrict__ KVh,
    unsigned short* __restrict__ out_pre)
{
  const int t  = threadIdx.x;
  const int pg = blockIdx.x * 8 + (t >> 5);   // b*16384 + y*128 + x
  const int b  = pg >> 14;
  const int yx = pg & 16383;
  const int y  = yx >> 7, x = yx & 127;
  const int c8 = t & 31;
  const int h  = c8 >> 2;

  const int ilo = max(0, (y - 1) >> 1), ihi = min(HT - 1, (y + 1) >> 1);
  const int jlo = max(0, (x - 1) >> 1), jhi = min(WT - 1, (x + 1) >> 1);

  float acc[8] = {};
  for (int i = ilo; i <= ihi; ++i)
    for (int j = jlo; j <= jhi; ++j) {
      const int w = i * WT + j;
      const int p = (y + 1 - 2 * i) * 4 + (x + 1 - 2 * j);
      const float rr = R[((size_t)(b * NWIN + w)) * 128 + h * NP2 + p];
      const uint4 v = *(const uint4*)(KVh + ((size_t)(b * NWIN + w)) * KVD + 256 + c8 * 8);
      const unsigned vv[4] = {v.x, v.y, v.z, v.w};
#pragma unroll
      for (int q = 0; q < 4; ++q) {
        acc[2*q]   = fmaf(rr, __uint_as_float(vv[q] << 16),         acc[2*q]);
        acc[2*q+1] = fmaf(rr, __uint_as_float(vv[q] & 0xffff0000u), acc[2*q+1]);
      }
    }

  uint4 ov;
  ov.x = (unsigned)f2bf(acc[0]) | ((unsigned)f2bf(acc[1]) << 16);
  ov.y = (unsigned)f2bf(acc[2]) | ((unsigned)f2bf(acc[3]) << 16);
  ov.z = (unsigned)f2bf(acc[4]) | ((unsigned)f2bf(acc[5]) << 16);
  ov.w = (unsigned)f2bf(acc[6]) | ((unsigned)f2bf(acc[7]) << 16);
  *(uint4*)(out_pre + (size_t)pg * DIM + c8 * 8) = ov;
}

// ---------------------------------------------------------------------------
extern "C" void kernel_launch(void* const* d_in, const int* in_sizes, int n_in,
                              void* d_out, int out_size, void* d_ws, size_t ws_size,
                              hipStream_t stream) {
  const float* Xt       = (const float*)d_in[0];
  const float* Xb       = (const float*)d_in[1];
  const float* q_w      = (const float*)d_in[2];
  const float* kv_w     = (const float*)d_in[3];
  const float* proj_w   = (const float*)d_in[4];
  const float* proj_b   = (const float*)d_in[5];
  const float* rel_init = (const float*)d_in[6];
  const float* rel_bias = (const float*)d_in[7];
  float* out = (float*)d_out;

  char* ws = (char*)d_ws;
  const size_t nXb = (size_t)B_ * NPIX * DIM;     // 16.78M
  const size_t nXt = (size_t)B_ * NWIN * KVD;     // 8.39M
  const size_t nQW = (size_t)DIM * DIM;
  const size_t nKVW = (size_t)KVD * KVD;
  unsigned short* Qh   = (unsigned short*)ws;  ws += nXb * 2;   // 32 MB (reused as Oh)
  unsigned short* Xth  = (unsigned short*)ws;  ws += nXt * 2;   // 16 MB (reused as R)
  unsigned short* KVh  = (unsigned short*)ws;  ws += nXt * 2;   // 16 MB
  float*          E    = (float*)ws;           ws += (size_t)B_ * NWIN * 128 * 4;   // 8 MB
  float*          S    = (float*)ws;           ws += (size_t)B_ * HEADS * NPIX * 4; // 2 MB
  unsigned short* qwh  = (unsigned short*)ws;  ws += nQW * 2;
  unsigned short* kvwh = (unsigned short*)ws;  ws += nKVW * 2;
  unsigned short* pwh  = (unsigned short*)ws;  ws += nQW * 2;
  float*          R    = (float*)Xth;   // alias: Xth dead after GEMM2
  unsigned short* Oh   = Qh;            // alias: Qh dead after es_kernel

  const dim3 blk(256);

  // 0) one merged cast: Xt + all three weights -> bf16
  cast_all<<<dim3(NCAST4 / 256), blk, 0, stream>>>(
      Xt, q_w, kv_w, proj_w, Xth, qwh, kvwh, pwh);

  // 1) Qh = Xb(fp32) @ q_w^T   (65536 x 256 x 256), fused-cast A staging
  gemm_af32<<<dim3(B_ * NPIX / 128, DIM / 128), blk, 0, stream>>>(
      Xb, qwh, Qh, B_ * NPIX, DIM, DIM);

  // 2) KVh = Xth @ kv_w^T      (16384 x 512 x 512)
  gemm_bf16<true, false><<<dim3(B_ * NWIN / 128, KVD / 128), blk, 0, stream>>>(
      Xth, kvwh, nullptr, KVh, B_ * NWIN, KVD, KVD);

  // 3) fused E + S (per-pixel q reuse, folded sum emitted directly)
  es_kernel<<<dim3(B_ * NPIX * HEADS / 256), blk, 0, stream>>>(
      Qh, KVh, rel_init, rel_bias, E, S);

  // 4) R = E / S_scrambled   [into Xth buffer]
  r_kernel<<<dim3(B_ * NWIN * 128 / 256), blk, 0, stream>>>(E, S, R);

  // 5) Oh = fold(R * v)      [bf16, into Qh buffer]
  o_kernel<<<dim3(B_ * NPIX / 8), blk, 0, stream>>>(R, KVh, Oh);

  // 6) out = Oh @ proj_w^T + proj_b   (fp32 out)
  gemm_bf16<false, true><<<dim3(B_ * NPIX / 128, DIM / 128), blk, 0, stream>>>(
      Oh, pwh, proj_b, out, B_ * NPIX, DIM, DIM);
}

// Round 5
// 253.308 us; speedup vs baseline: 2.4677x; 1.0345x over previous
//
#include <hip/hip_runtime.h>
#include <math.h>

// ---------------------------------------------------------------------------
// InterLevelAttention, MI355X. Fixed shapes from setup_inputs().
// Round 5: 128x256 GEMM tiles (A read once, 32 MFMA/barrier), v_perm bf16
// packing, A-reg prefetch pipelining, GEMM1+GEMM2 merged into one dispatch.
// ---------------------------------------------------------------------------
constexpr int B_    = 4;
constexpr int HT    = 64,  WT = 64;
constexpr int HB    = 128, WB = 128;
constexpr int DIM   = 256;
constexpr int KVD   = 512;
constexpr int HEADS = 8;
constexpr int NP2   = 16;
constexpr int NPIX  = HB * WB;       // 16384
constexpr int NWIN  = HT * WT;       // 4096
constexpr float SCALE = 0.17677669529663687f;  // 32^-0.5

using bf16x8 = __attribute__((ext_vector_type(8))) short;
using f32x4  = __attribute__((ext_vector_type(4))) float;

__device__ __forceinline__ unsigned short f2bf(float f) {
  union { float f; unsigned u; } v; v.f = f;
  unsigned r = v.u + 0x7fffu + ((v.u >> 16) & 1u);   // RNE
  return (unsigned short)(r >> 16);
}
// pack 2 fp32 -> 2 bf16 in one dword: round-half-away (+0x8000) + v_perm.
__device__ __forceinline__ unsigned pack_bf16(float x, float y) {
  unsigned ux = __float_as_uint(x) + 0x8000u;
  unsigned uy = __float_as_uint(y) + 0x8000u;
  return __builtin_amdgcn_perm(uy, ux, 0x07060302u);  // lo=hi16(ux), hi=hi16(uy)
}

// ---------------------------------------------------------------------------
// Merged fp32->bf16 cast: Xt + q_w + kv_w + proj_w in one launch.
// ---------------------------------------------------------------------------
constexpr int NXT4  = B_ * NWIN * KVD / 4;   // 2,097,152
constexpr int NQW4  = DIM * DIM / 4;         // 16,384
constexpr int NKVW4 = KVD * KVD / 4;         // 65,536
constexpr int NCAST4 = NXT4 + NQW4 + NKVW4 + NQW4;

__global__ __launch_bounds__(256) void cast_all(
    const float* __restrict__ Xt, const float* __restrict__ qw,
    const float* __restrict__ kvw, const float* __restrict__ pw,
    unsigned short* __restrict__ Xth, unsigned short* __restrict__ qwh,
    unsigned short* __restrict__ kvwh, unsigned short* __restrict__ pwh)
{
  const int i = blockIdx.x * 256 + threadIdx.x;
  const float* src; unsigned short* dst; int off;
  if (i < NXT4)                     { src = Xt;  dst = Xth;  off = i; }
  else if (i < NXT4 + NQW4)         { src = qw;  dst = qwh;  off = i - NXT4; }
  else if (i < NXT4 + NQW4 + NKVW4) { src = kvw; dst = kvwh; off = i - NXT4 - NQW4; }
  else                              { src = pw;  dst = pwh;  off = i - NXT4 - NQW4 - NKVW4; }
  float4 v = ((const float4*)src)[off];
  ushort4 o;
  o.x = f2bf(v.x); o.y = f2bf(v.y); o.z = f2bf(v.z); o.w = f2bf(v.w);
  ((ushort4*)dst)[off] = o;
}

// ---------------------------------------------------------------------------
// Templated MFMA GEMM core: C[M,N] = A[M,K] @ Bw[N,K]^T (+bias).
// BM=128, BK=32, BN in {128,256}. 256 thr = 4 waves (2x2).
// AF32: A is fp32, staged via reg-prefetch + perm-pack (pipelined);
// else A is bf16 via global_load_lds w=16. B always bf16 global_load_lds.
// ---------------------------------------------------------------------------
template<bool AF32, int BN, bool BF16_OUT, bool BIAS>
__device__ __forceinline__ void gemm_core(
    const void* __restrict__ Ap, const unsigned short* __restrict__ Bw,
    const float* __restrict__ bias, void* __restrict__ Cp,
    int M, int N, int K, int bx, int by,
    unsigned short* Ash, unsigned short* Bsh)
{
  constexpr int NT = BN / 32;          // n-frags per wave
  const int tid  = threadIdx.x;
  const int wave = tid >> 6;
  const int lane = tid & 63;
  const int m0 = bx * 128;
  const int n0 = by * BN;
  const int wm = (wave >> 1) * 64;
  const int wn = (wave & 1) * (BN / 2);

  f32x4 acc[4][NT];
#pragma unroll
  for (int i = 0; i < 4; ++i)
#pragma unroll
    for (int j = 0; j < NT; ++j) { f32x4 z = {0.f, 0.f, 0.f, 0.f}; acc[i][j] = z; }

  const float* Af = (const float*)Ap;
  float4 areg[4];
  auto loadA = [&](int kk) {
#pragma unroll
    for (int u = 0; u < 4; ++u) {
      const int c = u * 256 + tid, row = c >> 3, kq = (c & 7) * 4;
      areg[u] = *(const float4*)(Af + (size_t)(m0 + row) * K + kk + kq);
    }
  };
  if constexpr (AF32) loadA(0);

  const int fr = lane & 15;
  const int fk = (lane >> 4) * 8;

  for (int kk = 0; kk < K; kk += 32) {
    __syncthreads();                    // previous iter done reading LDS
    if constexpr (AF32) {
#pragma unroll
      for (int u = 0; u < 4; ++u) {
        const int c = u * 256 + tid, row = c >> 3, kq = (c & 7) * 4;
        uint2 pk;
        pk.x = pack_bf16(areg[u].x, areg[u].y);
        pk.y = pack_bf16(areg[u].z, areg[u].w);
        *(uint2*)&Ash[row * 32 + kq] = pk;
      }
    } else {
      const unsigned short* Ab = (const unsigned short*)Ap;
#pragma unroll
      for (int i = 0; i < 2; ++i) {
        const int c = i * 256 + wave * 64 + lane, row = c >> 2, ko = (c & 3) * 8;
        __builtin_amdgcn_global_load_lds(
            (const __attribute__((address_space(1))) unsigned int*)
                (Ab + (size_t)(m0 + row) * K + kk + ko),
            (__attribute__((address_space(3))) unsigned int*)
                ((char*)Ash + i * 4096 + wave * 1024),
            16, 0, 0);
      }
    }
#pragma unroll
    for (int i = 0; i < BN / 64; ++i) {
      const int c = i * 256 + wave * 64 + lane, row = c >> 2, ko = (c & 3) * 8;
      __builtin_amdgcn_global_load_lds(
          (const __attribute__((address_space(1))) unsigned int*)
              (Bw + (size_t)(n0 + row) * K + kk + ko),
          (__attribute__((address_space(3))) unsigned int*)
              ((char*)Bsh + i * 4096 + wave * 1024),
          16, 0, 0);
    }
    __syncthreads();                    // staging visible

    // pipelined A prefetch: reg loads issued in compute phase; their drain
    // happens at next iter's ds_write, overlapping MFMA with HBM latency.
    if constexpr (AF32) { if (kk + 32 < K) loadA(kk + 32); }

    bf16x8 af[4], bf[NT];
#pragma unroll
    for (int t = 0; t < 4; ++t)
      af[t] = *(const bf16x8*)&Ash[(wm + t * 16 + fr) * 32 + fk];
#pragma unroll
    for (int t = 0; t < NT; ++t)
      bf[t] = *(const bf16x8*)&Bsh[(wn + t * 16 + fr) * 32 + fk];
#pragma unroll
    for (int mt = 0; mt < 4; ++mt)
#pragma unroll
      for (int nt = 0; nt < NT; ++nt)
        acc[mt][nt] = __builtin_amdgcn_mfma_f32_16x16x32_bf16(
            af[mt], bf[nt], acc[mt][nt], 0, 0, 0);
  }

  // epilogue: C/D layout col=lane&15, row=(lane>>4)*4+reg
  const int col0 = lane & 15;
  const int rb   = (lane >> 4) * 4;
#pragma unroll
  for (int mt = 0; mt < 4; ++mt)
#pragma unroll
    for (int nt = 0; nt < NT; ++nt) {
      const int col = n0 + wn + nt * 16 + col0;
      float bv = BIAS ? bias[col] : 0.f;
#pragma unroll
      for (int r = 0; r < 4; ++r) {
        const int row = m0 + wm + mt * 16 + rb + r;
        const float v = acc[mt][nt][r] + bv;
        if (BF16_OUT) ((unsigned short*)Cp)[(size_t)row * N + col] = f2bf(v);
        else          ((float*)Cp)[(size_t)row * N + col] = v;
      }
    }
}

// ---------------------------------------------------------------------------
// Merged GEMM1 (Q proj, fp32 A, 128x256) + GEMM2 (KV proj, bf16, 128x128).
// Even block ids -> G1 (512), odd -> G2 (512): each CU hosts both kinds.
// ---------------------------------------------------------------------------
__global__ __launch_bounds__(256, 2) void g12_kernel(
    const float* __restrict__ Xb, const unsigned short* __restrict__ qwh,
    unsigned short* __restrict__ Qh,
    const unsigned short* __restrict__ Xth, const unsigned short* __restrict__ kvwh,
    unsigned short* __restrict__ KVh)
{
  __shared__ unsigned short Ash[128 * 32];
  __shared__ unsigned short Bsh[256 * 32];
  const int id = blockIdx.x;
  if ((id & 1) == 0) {
    gemm_core<true, 256, true, false>(Xb, qwh, nullptr, Qh,
        B_ * NPIX, DIM, DIM, id >> 1, 0, Ash, Bsh);
  } else {
    const int t = id >> 1;
    gemm_core<false, 128, true, false>(Xth, kvwh, nullptr, KVh,
        B_ * NWIN, KVD, KVD, t >> 2, t & 3, Ash, Bsh);
  }
}

// GEMM3: out proj, bf16 A, 128x256, fp32 out + bias.
__global__ __launch_bounds__(256, 2) void g3_kernel(
    const unsigned short* __restrict__ Oh, const unsigned short* __restrict__ pwh,
    const float* __restrict__ pb, float* __restrict__ out)
{
  __shared__ unsigned short Ash[128 * 32];
  __shared__ unsigned short Bsh[256 * 32];
  gemm_core<false, 256, false, true>(Oh, pwh, pb, out,
      B_ * NPIX, DIM, DIM, blockIdx.x, 0, Ash, Bsh);
}

// ---------------------------------------------------------------------------
// Fused e+s: one thread per (b, pixel, h). q loaded once; E contributions for
// the <=4 covering windows + folded sum S emitted directly.
// ---------------------------------------------------------------------------
__global__ __launch_bounds__(256) void es_kernel(
    const unsigned short* __restrict__ Qh, const unsigned short* __restrict__ KVh,
    const float* __restrict__ rel_init, const float* __restrict__ rel_bias,
    float* __restrict__ E, float* __restrict__ S)
{
  const int idx = blockIdx.x * 256 + threadIdx.x;
  const int h = idx & 7;
  const int x = (idx >> 3) & 127;
  const int y = (idx >> 10) & 127;
  const int b = idx >> 17;

  const uint4* qp = (const uint4*)(Qh + ((size_t)((b << 14) + y * WB + x)) * DIM + h * 32);
  uint4 q0 = qp[0], q1 = qp[1], q2 = qp[2], q3 = qp[3];
  const unsigned qa[16] = {q0.x,q0.y,q0.z,q0.w, q1.x,q1.y,q1.z,q1.w,
                           q2.x,q2.y,q2.z,q2.w, q3.x,q3.y,q3.z,q3.w};

  const int ilo = max(0, (y - 1) >> 1), ihi = min(HT - 1, (y + 1) >> 1);
  const int jlo = max(0, (x - 1) >> 1), jhi = min(WT - 1, (x + 1) >> 1);

  float s = 0.f;
  for (int i = ilo; i <= ihi; ++i)
    for (int j = jlo; j <= jhi; ++j) {
      const int w = i * WT + j;
      const int p = (y + 1 - 2 * i) * 4 + (x + 1 - 2 * j);
      const uint4* kp = (const uint4*)(KVh + ((size_t)((b << 12) + w)) * KVD + h * 32);
      uint4 k0 = kp[0], k1 = kp[1], k2 = kp[2], k3 = kp[3];
      const unsigned ka[16] = {k0.x,k0.y,k0.z,k0.w, k1.x,k1.y,k1.z,k1.w,
                               k2.x,k2.y,k2.z,k2.w, k3.x,k3.y,k3.z,k3.w};
      float acc = 0.f;
#pragma unroll
      for (int q = 0; q < 16; ++q) {
        acc = fmaf(__uint_as_float(qa[q] << 16),
                   __uint_as_float(ka[q] << 16), acc);
        acc = fmaf(__uint_as_float(qa[q] & 0xffff0000u),
                   __uint_as_float(ka[q] & 0xffff0000u), acc);
      }
      const float e = expf(acc * SCALE + rel_init[p] + rel_bias[p]);
      E[((size_t)((b << 12) + w)) * 128 + h * NP2 + p] = e;
      s += e;
    }
  S[(size_t)((b * HEADS + h) << 14) + y * WB + x] = s;
}

// ---------------------------------------------------------------------------
// R[b,w,h,p] = E / S_scrambled (faithful to reference reshape quirk):
// h_eff = w>>9; w_eff = (w&511)*8 + h; p_eff = p; padding divisor -> 1.
// ---------------------------------------------------------------------------
__global__ __launch_bounds__(256) void r_kernel(
    const float* __restrict__ E, const float* __restrict__ S,
    float* __restrict__ R)
{
  const int idx = blockIdx.x * 256 + threadIdx.x;
  const int b  = idx >> 19;
  const int r  = idx & 524287;
  const int w  = r >> 7;
  const int t7 = r & 127;
  const int h  = t7 >> 4, p = t7 & 15;

  const int h_eff = w >> 9;
  const int w_eff = ((w & 511) << 3) + h;
  const int i2 = w_eff >> 6, j2 = w_eff & 63;
  const int y2 = 2 * i2 + (p >> 2) - 1;
  const int x2 = 2 * j2 + (p & 3) - 1;
  float s = 1.f;
  if ((unsigned)y2 < (unsigned)HB && (unsigned)x2 < (unsigned)WB)
    s = S[(size_t)((b * HEADS + h_eff) * NPIX) + y2 * WB + x2];
  R[idx] = E[idx] / s;
}

// ---------------------------------------------------------------------------
// out_pre[b,pix,c] (bf16) = sum over covering windows of R * v.
// 8 channels/thread, 32 threads/pixel, 8 pixels/block.
// ---------------------------------------------------------------------------
__global__ __launch_bounds__(256) void o_kernel(
    const float* __restrict__ R, const unsigned short* __restrict__ KVh,
    unsigned short* __restrict__ out_pre)
{
  const int t  = threadIdx.x;
  const int pg = blockIdx.x * 8 + (t >> 5);
  const int b  = pg >> 14;
  const int yx = pg & 16383;
  const int y  = yx >> 7, x = yx & 127;
  const int c8 = t & 31;
  const int h  = c8 >> 2;

  const int ilo = max(0, (y - 1) >> 1), ihi = min(HT - 1, (y + 1) >> 1);
  const int jlo = max(0, (x - 1) >> 1), jhi = min(WT - 1, (x + 1) >> 1);

  float acc[8] = {};
  for (int i = ilo; i <= ihi; ++i)
    for (int j = jlo; j <= jhi; ++j) {
      const int w = i * WT + j;
      const int p = (y + 1 - 2 * i) * 4 + (x + 1 - 2 * j);
      const float rr = R[((size_t)(b * NWIN + w)) * 128 + h * NP2 + p];
      const uint4 v = *(const uint4*)(KVh + ((size_t)(b * NWIN + w)) * KVD + 256 + c8 * 8);
      const unsigned vv[4] = {v.x, v.y, v.z, v.w};
#pragma unroll
      for (int q = 0; q < 4; ++q) {
        acc[2*q]   = fmaf(rr, __uint_as_float(vv[q] << 16),         acc[2*q]);
        acc[2*q+1] = fmaf(rr, __uint_as_float(vv[q] & 0xffff0000u), acc[2*q+1]);
      }
    }

  uint4 ov;
  ov.x = (unsigned)f2bf(acc[0]) | ((unsigned)f2bf(acc[1]) << 16);
  ov.y = (unsigned)f2bf(acc[2]) | ((unsigned)f2bf(acc[3]) << 16);
  ov.z = (unsigned)f2bf(acc[4]) | ((unsigned)f2bf(acc[5]) << 16);
  ov.w = (unsigned)f2bf(acc[6]) | ((unsigned)f2bf(acc[7]) << 16);
  *(uint4*)(out_pre + (size_t)pg * DIM + c8 * 8) = ov;
}

// ---------------------------------------------------------------------------
extern "C" void kernel_launch(void* const* d_in, const int* in_sizes, int n_in,
                              void* d_out, int out_size, void* d_ws, size_t ws_size,
                              hipStream_t stream) {
  const float* Xt       = (const float*)d_in[0];
  const float* Xb       = (const float*)d_in[1];
  const float* q_w      = (const float*)d_in[2];
  const float* kv_w     = (const float*)d_in[3];
  const float* proj_w   = (const float*)d_in[4];
  const float* proj_b   = (const float*)d_in[5];
  const float* rel_init = (const float*)d_in[6];
  const float* rel_bias = (const float*)d_in[7];
  float* out = (float*)d_out;

  char* ws = (char*)d_ws;
  const size_t nXb = (size_t)B_ * NPIX * DIM;
  const size_t nXt = (size_t)B_ * NWIN * KVD;
  const size_t nQW = (size_t)DIM * DIM;
  const size_t nKVW = (size_t)KVD * KVD;
  unsigned short* Qh   = (unsigned short*)ws;  ws += nXb * 2;   // 32 MB (reused as Oh)
  unsigned short* Xth  = (unsigned short*)ws;  ws += nXt * 2;   // 16 MB (reused as R)
  unsigned short* KVh  = (unsigned short*)ws;  ws += nXt * 2;   // 16 MB
  float*          E    = (float*)ws;           ws += (size_t)B_ * NWIN * 128 * 4;   // 8 MB
  float*          S    = (float*)ws;           ws += (size_t)B_ * HEADS * NPIX * 4; // 2 MB
  unsigned short* qwh  = (unsigned short*)ws;  ws += nQW * 2;
  unsigned short* kvwh = (unsigned short*)ws;  ws += nKVW * 2;
  unsigned short* pwh  = (unsigned short*)ws;  ws += nQW * 2;
  float*          R    = (float*)Xth;   // alias: Xth dead after g12
  unsigned short* Oh   = Qh;            // alias: Qh dead after es_kernel

  const dim3 blk(256);

  // 0) merged cast: Xt + all three weights -> bf16
  cast_all<<<dim3(NCAST4 / 256), blk, 0, stream>>>(
      Xt, q_w, kv_w, proj_w, Xth, qwh, kvwh, pwh);

  // 1+2) merged Q proj (fp32 A, pipelined) + KV proj
  g12_kernel<<<dim3(1024), blk, 0, stream>>>(Xb, qwh, Qh, Xth, kvwh, KVh);

  // 3) fused E + S
  es_kernel<<<dim3(B_ * NPIX * HEADS / 256), blk, 0, stream>>>(
      Qh, KVh, rel_init, rel_bias, E, S);

  // 4) R = E / S_scrambled   [into Xth buffer]
  r_kernel<<<dim3(B_ * NWIN * 128 / 256), blk, 0, stream>>>(E, S, R);

  // 5) Oh = fold(R * v)      [bf16, into Qh buffer]
  o_kernel<<<dim3(B_ * NPIX / 8), blk, 0, stream>>>(R, KVh, Oh);

  // 6) out = Oh @ proj_w^T + proj_b
  g3_kernel<<<dim3(B_ * NPIX / 128), blk, 0, stream>>>(Oh, pwh, proj_b, out);
}